// Round 2
// 217.765 us; speedup vs baseline: 1.3253x; 1.3253x over previous
//
#include <hip/hip_runtime.h>
#include <hip/hip_bf16.h>
#include <math.h>

// Problem constants
#define C_DIM 256      // channels
#define SPAT 4096      // h*w = 64*64
#define HEADS_N 8
#define DHEAD 64
#define MEMTOK 4
#define TTOK 4100      // MEMTOK + SPAT
#define TTOKP 4160     // padded to 65 tiles of 64
#define HID 512        // HEADS_N * DHEAD
#define PSP 72         // Ps LDS row pitch in bf16 elems (144 B; keeps 16B align for b128)

typedef __bf16 bf16x8 __attribute__((ext_vector_type(8)));
typedef unsigned short u16x8 __attribute__((ext_vector_type(8)));
typedef float f32x4 __attribute__((ext_vector_type(4)));

static __device__ inline unsigned short f2bf(float f) {  // RNE f32->bf16
    unsigned int u = __float_as_uint(f);
    u += 0x7fffu + ((u >> 16) & 1u);
    return (unsigned short)(u >> 16);
}

static __device__ inline bf16x8 ldb8(const unsigned short* p) {
    union { u16x8 u; bf16x8 b; } t;
    t.u = *(const u16x8*)p;
    return t.b;
}

static __device__ inline unsigned int pkbf(float a, float b) {  // packed bf16 pair
    union { __bf16 h[2]; unsigned int u; } t;
    t.h[0] = (__bf16)a; t.h[1] = (__bf16)b;
    return t.u;
}

// async global->LDS, 16B per lane (LDS dest = wave-uniform base + lane*16)
static __device__ inline void gload16(const void* g, void* l) {
    __builtin_amdgcn_global_load_lds(
        (const __attribute__((address_space(1))) unsigned int*)g,
        (__attribute__((address_space(3))) unsigned int*)l, 16, 0, 0);
}

// ---------------------------------------------------------------------------
// Kernel 1: RMSNorm over channel axis; 64 pixels/block, 4 channel-groups.
// ---------------------------------------------------------------------------
__global__ __launch_bounds__(256) void rmsnorm_kernel(const float* __restrict__ x,
                                                      const float* __restrict__ gamma,
                                                      float* __restrict__ xn) {
    int p = blockIdx.x * 64 + (threadIdx.x & 63);
    int g = threadIdx.x >> 6;           // 0..3 channel group
    float ss = 0.f;
    for (int c = g * 64; c < g * 64 + 64; ++c) {
        float v = x[c * SPAT + p];
        ss += v * v;
    }
    __shared__ float red[4][64];
    red[g][threadIdx.x & 63] = ss;
    __syncthreads();
    int lp = threadIdx.x & 63;
    float tot = red[0][lp] + red[1][lp] + red[2][lp] + red[3][lp];
    float inv = rsqrtf(tot) * 16.0f;    // * sqrt(256)/norm
    for (int c = g * 64; c < g * 64 + 64; ++c)
        xn[c * SPAT + p] = x[c * SPAT + p] * inv * (gamma[c] + 1.0f);
}

// ---------------------------------------------------------------------------
// Kernel 2: mem_kv copy (bf16) + zero-fill pad rows/cols (ws is re-poisoned!)
// kb: [h][TTOKP][64] bf16, rows 0..3 = mem k, rows 4100..4159 zero
// vtb: [h][64][TTOKP] bf16 (transposed), cols 0..3 = mem v, cols 4100.. zero
// ---------------------------------------------------------------------------
__global__ __launch_bounds__(256) void fixup_kernel(const float* __restrict__ mem,
                                                    unsigned short* __restrict__ kb,
                                                    unsigned short* __restrict__ vtb) {
    int i = blockIdx.x * 256 + threadIdx.x;
    if (i < 4096) {
        int d = i & 63, m = (i >> 6) & 3, h = (i >> 8) & 7, s = (i >> 11) & 1;
        unsigned short val = f2bf(mem[i]);
        if (s == 0) kb[(size_t)h * TTOKP * 64 + m * 64 + d] = val;
        else        vtb[((size_t)h * 64 + d) * TTOKP + m] = val;
    } else {
        int z = i - 4096;              // 0..61439
        if (z < 30720) {               // kb pad rows
            int h = z / 3840, r = z % 3840;
            int row = TTOK + r / 64, d = r % 64;
            kb[(size_t)h * TTOKP * 64 + row * 64 + d] = 0;
        } else {                       // vtb pad cols
            z -= 30720;
            int h = z / 3840, r = z % 3840;
            int d = r / 60, tcol = TTOK + r % 60;
            vtb[((size_t)h * 64 + d) * TTOKP + tcol] = 0;
        }
    }
}

// ---------------------------------------------------------------------------
// Kernel 3: QKV GEMM (fp32 compute, bf16 outputs).
// q section gets folded scale 0.125*log2(e) (softmax scale + exp2 domain).
// q: [h][4096][64]; k: [h][TTOKP][64] (rows 4..4099); v: [h][64][TTOKP] transposed.
// ---------------------------------------------------------------------------
__global__ __launch_bounds__(256) void qkv_gemm(const float* __restrict__ w,
                                                const float* __restrict__ xn,
                                                unsigned short* __restrict__ qb,
                                                unsigned short* __restrict__ kb,
                                                unsigned short* __restrict__ vtb) {
    int tile_p = blockIdx.x;            // 0..63
    int tile_o = blockIdx.y;            // 0..23
    int o0 = tile_o * 64, p0 = tile_p * 64;
    __shared__ float wt[16][68];        // [lc][lo]
    __shared__ float xt[16][68];        // [lc][lp]
    int t = threadIdx.x;
    int tx = t & 15, ty = t >> 4;
    float acc[4][4];
#pragma unroll
    for (int i = 0; i < 4; ++i)
#pragma unroll
        for (int j = 0; j < 4; ++j) acc[i][j] = 0.f;

    for (int c0 = 0; c0 < C_DIM; c0 += 16) {
        __syncthreads();
        {   // w tile (64 o x 16 c), transposed
            int lo = t >> 2, lc4 = (t & 3) * 4;
            float4 wv = *(const float4*)&w[(size_t)(o0 + lo) * C_DIM + c0 + lc4];
            wt[lc4 + 0][lo] = wv.x; wt[lc4 + 1][lo] = wv.y;
            wt[lc4 + 2][lo] = wv.z; wt[lc4 + 3][lo] = wv.w;
        }
        {   // xn tile (16 c x 64 p)
            int lc = t >> 4, lp4 = (t & 15) * 4;
            *(float4*)&xt[lc][lp4] = *(const float4*)&xn[(size_t)(c0 + lc) * SPAT + p0 + lp4];
        }
        __syncthreads();
#pragma unroll
        for (int lc = 0; lc < 16; ++lc) {
            float4 a4 = *(float4*)&wt[lc][tx * 4];
            float4 b4 = *(float4*)&xt[lc][ty * 4];
            float av[4] = {a4.x, a4.y, a4.z, a4.w};
            float bv[4] = {b4.x, b4.y, b4.z, b4.w};
#pragma unroll
            for (int i = 0; i < 4; ++i)
#pragma unroll
                for (int j = 0; j < 4; ++j) acc[i][j] += av[i] * bv[j];
        }
    }
    int sec = tile_o >> 3, h = tile_o & 7;
    if (sec == 0) {
        const float QSC = 0.125f * 1.4426950408889634f;
        unsigned short* dst = qb + (size_t)h * SPAT * 64;
#pragma unroll
        for (int j = 0; j < 4; ++j) {
            int p = p0 + ty * 4 + j;
            ushort4 val = {f2bf(acc[0][j] * QSC), f2bf(acc[1][j] * QSC),
                           f2bf(acc[2][j] * QSC), f2bf(acc[3][j] * QSC)};
            *(ushort4*)&dst[(size_t)p * 64 + tx * 4] = val;
        }
    } else if (sec == 1) {
        unsigned short* dst = kb + (size_t)h * TTOKP * 64;
#pragma unroll
        for (int j = 0; j < 4; ++j) {
            int tt = MEMTOK + p0 + ty * 4 + j;
            ushort4 val = {f2bf(acc[0][j]), f2bf(acc[1][j]),
                           f2bf(acc[2][j]), f2bf(acc[3][j])};
            *(ushort4*)&dst[(size_t)tt * 64 + tx * 4] = val;
        }
    } else {  // v transposed: [d][t]
        unsigned short* dst = vtb + (size_t)h * 64 * TTOKP;
        int t0 = MEMTOK + p0 + ty * 4;
#pragma unroll
        for (int i = 0; i < 4; ++i) {
            int d = tx * 4 + i;
            ushort4 val = {f2bf(acc[i][0]), f2bf(acc[i][1]),
                           f2bf(acc[i][2]), f2bf(acc[i][3])};
            *(ushort4*)&dst[(size_t)d * TTOKP + t0] = val;
        }
    }
}

// ---------------------------------------------------------------------------
// Kernel 4: flash attention, bf16 MFMA (16x16x32), fp32 accum.
// Swapped-operand form: QK^T computed as mfma(K,Q) -> S^T (lane owns one q-row),
// PV computed as mfma(V^T,P) -> O^T[d][q]. Softmax reduce = 15 local fmax + 2 shfl.
// K/V tiles DOUBLE-buffered via global_load_lds (async DMA). 2-phase schedule:
// STAGE(t+1) issued at the TOP of each tile (overlaps compute of tile t);
// one FUSED "s_waitcnt vmcnt(0); s_barrier" asm at the BOTTOM (race-proof:
// nothing can be scheduled between the drain and the barrier, and the memory
// clobber pins LDS reads / DMA issues on the correct side).
// LDS layout is linear; XOR swizzle (col16B ^= row&7) applied on the GLOBAL
// source addr and on the ds_read addr (both-sides swizzle, gload_lds-safe).
// Output ob is [h][64 d][4096 p] fp32.
// ---------------------------------------------------------------------------
__global__ __launch_bounds__(256) void attn_mfma(const unsigned short* __restrict__ qb,
                                                 const unsigned short* __restrict__ kb,
                                                 const unsigned short* __restrict__ vtb,
                                                 float* __restrict__ ob) {
    const int h  = blockIdx.x & 7;           // head = bid%8 -> all blocks of a head on one XCD
    const int p0 = (blockIdx.x >> 3) * 64;

    __shared__ unsigned short Ks0[64 * 64], Ks1[64 * 64];
    __shared__ unsigned short Vs0[64 * 64], Vs1[64 * 64];
    __shared__ __bf16 Psb[4 * 16 * PSP];

    const int t = threadIdx.x;
    const int w = t >> 6;
    const int lane = t & 63;
    const int col16 = lane & 15;
    const int quad = lane >> 4;

    const unsigned short* qh = qb + (size_t)h * SPAT * 64;
    const char* khb = (const char*)(kb + (size_t)h * TTOKP * 64);
    const char* vhb = (const char*)(vtb + (size_t)h * 64 * TTOKP);
    float* ohd = ob + (size_t)h * 64 * SPAT;

    // staging geometry: LDS byte b = w*2048 + i*1024 + lane*16 -> row = b>>7,
    // tile-col byte = (b&127); global source pre-swizzled by ((row&7)<<4).
    const int srow = w * 16 + (lane >> 3);                       // chunk i adds +8
    const int scol = (((lane & 7) ^ ((lane >> 3) & 7)) << 4);

    // fragment-read swizzle: row&7 == col16&7 for rows nt*16+col16
    const int cswz = col16 & 7;
    const int sw0 = ((quad ^ cswz) << 4);
    const int sw1 = (((quad + 4) ^ cswz) << 4);
    const int rB = col16 * 128;

    // Q fragments (kernel-lifetime registers); q-row = p0 + w*16 + col16
    bf16x8 aq0 = ldb8(&qh[(size_t)(p0 + w * 16 + col16) * 64 + quad * 8]);
    bf16x8 aq1 = ldb8(&qh[(size_t)(p0 + w * 16 + col16) * 64 + 32 + quad * 8]);

    float m_i = -1e30f, l_i = 0.f;
    f32x4 Oa[4];
#pragma unroll
    for (int n = 0; n < 4; ++n) Oa[n] = (f32x4){0.f, 0.f, 0.f, 0.f};

    __bf16* pw = &Psb[(w * 16 + col16) * PSP];
    const unsigned short* pr = (const unsigned short*)pw;

    auto STAGE = [&](int tb, unsigned short* Kd, unsigned short* Vd) {
        size_t kro = ((size_t)tb * 64 + srow) * 128 + scol;
        gload16(khb + kro,        (char*)Kd + w * 2048);
        gload16(khb + kro + 1024, (char*)Kd + w * 2048 + 1024);        // rows +8
        size_t vro = (size_t)srow * (TTOKP * 2) + (size_t)tb * 128 + scol;
        gload16(vhb + vro,                           (char*)Vd + w * 2048);
        gload16(vhb + vro + (size_t)8 * (TTOKP * 2), (char*)Vd + w * 2048 + 1024);
    };

    auto STEP = [&](int tile, const unsigned short* Kc_, const unsigned short* Vc_,
                    unsigned short* Ksn, unsigned short* Vsn, bool stage, bool last) {
        // issue next tile's DMA first: lands under this tile's compute
        if (stage) STAGE(tile + 1, Ksn, Vsn);

        const char* Kc = (const char*)Kc_;
        const char* Vc = (const char*)Vc_;

        // S^T = K Q^T : sv[n][r] = S^T[key = n*16+quad*4+r][q = col16]
        f32x4 sv[4];
#pragma unroll
        for (int n = 0; n < 4; ++n) {
            sv[n] = (f32x4){0.f, 0.f, 0.f, 0.f};
            bf16x8 bk0 = ldb8((const unsigned short*)(Kc + n * 2048 + rB + sw0));
            bf16x8 bk1 = ldb8((const unsigned short*)(Kc + n * 2048 + rB + sw1));
            sv[n] = __builtin_amdgcn_mfma_f32_16x16x32_bf16(bk0, aq0, sv[n], 0, 0, 0);
            sv[n] = __builtin_amdgcn_mfma_f32_16x16x32_bf16(bk1, aq1, sv[n], 0, 0, 0);
        }

        if (last) {   // tile 64: only keys 0..3 valid (n==0 && quad==0)
#pragma unroll
            for (int n = 0; n < 4; ++n)
#pragma unroll
                for (int r = 0; r < 4; ++r)
                    if ((n | quad) != 0) sv[n][r] = -1e30f;
        }

        // per-q-row softmax: 15 local fmax + xor16/xor32 (4 quads hold the 64 keys)
        float rm = fmaxf(
            fmaxf(fmaxf(fmaxf(sv[0][0], sv[0][1]), fmaxf(sv[0][2], sv[0][3])),
                  fmaxf(fmaxf(sv[1][0], sv[1][1]), fmaxf(sv[1][2], sv[1][3]))),
            fmaxf(fmaxf(fmaxf(sv[2][0], sv[2][1]), fmaxf(sv[2][2], sv[2][3])),
                  fmaxf(fmaxf(sv[3][0], sv[3][1]), fmaxf(sv[3][2], sv[3][3]))));
        rm = fmaxf(rm, __shfl_xor(rm, 16, 64));
        rm = fmaxf(rm, __shfl_xor(rm, 32, 64));

        float mn = fmaxf(m_i, rm);
        float al = __builtin_amdgcn_exp2f(m_i - mn);
        m_i = mn;

        float rs = 0.f;
#pragma unroll
        for (int n = 0; n < 4; ++n) {
            float e0 = __builtin_amdgcn_exp2f(sv[n][0] - mn);
            float e1 = __builtin_amdgcn_exp2f(sv[n][1] - mn);
            float e2 = __builtin_amdgcn_exp2f(sv[n][2] - mn);
            float e3 = __builtin_amdgcn_exp2f(sv[n][3] - mn);
            rs += (e0 + e1) + (e2 + e3);
            *(unsigned int*)&pw[n * 16 + quad * 4]     = pkbf(e0, e1);
            *(unsigned int*)&pw[n * 16 + quad * 4 + 2] = pkbf(e2, e3);
        }
        rs += __shfl_xor(rs, 16, 64);
        rs += __shfl_xor(rs, 32, 64);
        l_i = l_i * al + rs;

#pragma unroll
        for (int n = 0; n < 4; ++n) {
            Oa[n][0] *= al; Oa[n][1] *= al; Oa[n][2] *= al; Oa[n][3] *= al;
        }

        // P fragment (same-wave LDS roundtrip, per-wave private region)
        bf16x8 pa0 = ldb8(pr + quad * 8);
        bf16x8 pa1 = ldb8(pr + 32 + quad * 8);

        // O^T += V^T P^T : Oa[n][r] = O^T[d = n*16+quad*4+r][q = col16]
#pragma unroll
        for (int n = 0; n < 4; ++n) {
            bf16x8 bv0 = ldb8((const unsigned short*)(Vc + n * 2048 + rB + sw0));
            bf16x8 bv1 = ldb8((const unsigned short*)(Vc + n * 2048 + rB + sw1));
            Oa[n] = __builtin_amdgcn_mfma_f32_16x16x32_bf16(bv0, pa0, Oa[n], 0, 0, 0);
            Oa[n] = __builtin_amdgcn_mfma_f32_16x16x32_bf16(bv1, pa1, Oa[n], 0, 0, 0);
        }

        if (!last) {
            // fused drain+barrier: indivisible, memory-clobbered
            asm volatile("s_waitcnt vmcnt(0)\n\ts_barrier" ::: "memory");
            __builtin_amdgcn_sched_barrier(0);
        }
    };

    // prologue: stage tile 0, drain, barrier (fused)
    STAGE(0, Ks0, Vs0);
    asm volatile("s_waitcnt vmcnt(0)\n\ts_barrier" ::: "memory");
    __builtin_amdgcn_sched_barrier(0);

    // tiles 0..63 in pairs with statically-named buffers; tile 64 separate
    for (int b = 0; b < 64; b += 2) {
        STEP(b,     Ks0, Vs0, Ks1, Vs1, true, false);
        STEP(b + 1, Ks1, Vs1, Ks0, Vs0, true, false);
    }
    STEP(64, Ks0, Vs0, Ks1, Vs1, false, true);     // last: no stage, masked

    // epilogue: O^T / l -> ob[h][d][p]
    float inv = 1.0f / l_i;
    int p = p0 + w * 16 + col16;
#pragma unroll
    for (int n = 0; n < 4; ++n)
#pragma unroll
        for (int r = 0; r < 4; ++r)
            ohd[(size_t)(n * 16 + quad * 4 + r) * SPAT + p] = Oa[n][r] * inv;
}

// ---------------------------------------------------------------------------
// Kernel 5: out projection (fp32): out[oc,p] = sum_{h,d} w_out[oc,h*64+d]*ob[h][d][p]
// ob is [h][d][p] -> B-tile load is a plain coalesced row copy.
// ---------------------------------------------------------------------------
__global__ __launch_bounds__(256) void out_gemm(const float* __restrict__ w,
                                                const float* __restrict__ ob,
                                                float* __restrict__ out) {
    int p0 = blockIdx.x * 64;
    int o0 = blockIdx.y * 64;
    __shared__ float at[16][68];
    __shared__ float bt[16][68];
    int t = threadIdx.x;
    int tx = t & 15, ty = t >> 4;
    float acc[4][4];
#pragma unroll
    for (int i = 0; i < 4; ++i)
#pragma unroll
        for (int j = 0; j < 4; ++j) acc[i][j] = 0.f;

    for (int c0 = 0; c0 < HID; c0 += 16) {
        int hh = c0 >> 6;
        int d0 = c0 & 63;
        __syncthreads();
        {
            int lo = t >> 2, lc4 = (t & 3) * 4;
            float4 wv = *(const float4*)&w[(size_t)(o0 + lo) * HID + c0 + lc4];
            at[lc4 + 0][lo] = wv.x; at[lc4 + 1][lo] = wv.y;
            at[lc4 + 2][lo] = wv.z; at[lc4 + 3][lo] = wv.w;
        }
        {
            int lc = t >> 4, lp4 = (t & 15) * 4;
            *(float4*)&bt[lc][lp4] =
                *(const float4*)&ob[((size_t)hh * 64 + d0 + lc) * SPAT + p0 + lp4];
        }
        __syncthreads();
#pragma unroll
        for (int lc = 0; lc < 16; ++lc) {
            float4 a4 = *(float4*)&at[lc][tx * 4];
            float4 b4 = *(float4*)&bt[lc][ty * 4];
            float av[4] = {a4.x, a4.y, a4.z, a4.w};
            float bv[4] = {b4.x, b4.y, b4.z, b4.w};
#pragma unroll
            for (int i = 0; i < 4; ++i)
#pragma unroll
                for (int j = 0; j < 4; ++j) acc[i][j] += av[i] * bv[j];
        }
    }
#pragma unroll
    for (int i = 0; i < 4; ++i) {
        float4 val = {acc[i][0], acc[i][1], acc[i][2], acc[i][3]};
        *(float4*)&out[(size_t)(o0 + tx * 4 + i) * SPAT + p0 + ty * 4] = val;
    }
}

// ---------------------------------------------------------------------------
// Launch
// ---------------------------------------------------------------------------
extern "C" void kernel_launch(void* const* d_in, const int* in_sizes, int n_in,
                              void* d_out, int out_size, void* d_ws, size_t ws_size,
                              hipStream_t stream) {
    const float* x      = (const float*)d_in[0];
    const float* gamma  = (const float*)d_in[1];
    const float* mem_kv = (const float*)d_in[2];
    const float* w_qkv  = (const float*)d_in[3];
    const float* w_out  = (const float*)d_in[4];
    float* out = (float*)d_out;

    // workspace: xn(f32) | qb(bf16) | kb(bf16) | vtb(bf16) | ob(f32)  ~25 MB
    float* xn = (float*)d_ws;
    unsigned short* qb  = (unsigned short*)(xn + (size_t)C_DIM * SPAT);
    unsigned short* kb  = qb + (size_t)HEADS_N * SPAT * DHEAD;
    unsigned short* vtb = kb + (size_t)HEADS_N * TTOKP * DHEAD;
    float* ob = (float*)(vtb + (size_t)HEADS_N * DHEAD * TTOKP);

    rmsnorm_kernel<<<dim3(64), 256, 0, stream>>>(x, gamma, xn);
    fixup_kernel<<<dim3(256), 256, 0, stream>>>(mem_kv, kb, vtb);
    qkv_gemm<<<dim3(64, 24), 256, 0, stream>>>(w_qkv, xn, qb, kb, vtb);
    attn_mfma<<<dim3(512), 256, 0, stream>>>(qb, kb, vtb, ob);
    out_gemm<<<dim3(64, 4), 256, 0, stream>>>(w_out, ob, out);
}

// Round 3
// 205.841 us; speedup vs baseline: 1.4021x; 1.0579x over previous
//
#include <hip/hip_runtime.h>
#include <hip/hip_bf16.h>
#include <math.h>

// Problem constants
#define C_DIM 256      // channels
#define SPAT 4096      // h*w = 64*64
#define HEADS_N 8
#define DHEAD 64
#define MEMTOK 4
#define TTOK 4100      // MEMTOK + SPAT
#define TTOKP 4160     // padded to 65 tiles of 64
#define HID 512        // HEADS_N * DHEAD
#define PSP 72         // Ps LDS row pitch in bf16 elems (144 B; keeps 16B align for b128)

typedef __bf16 bf16x8 __attribute__((ext_vector_type(8)));
typedef unsigned short u16x8 __attribute__((ext_vector_type(8)));
typedef float f32x4 __attribute__((ext_vector_type(4)));

static __device__ inline unsigned short f2bf(float f) {  // RNE f32->bf16
    unsigned int u = __float_as_uint(f);
    u += 0x7fffu + ((u >> 16) & 1u);
    return (unsigned short)(u >> 16);
}

static __device__ inline bf16x8 ldb8(const unsigned short* p) {
    union { u16x8 u; bf16x8 b; } t;
    t.u = *(const u16x8*)p;
    return t.b;
}

static __device__ inline unsigned int pkbf(float a, float b) {  // packed bf16 pair
    union { __bf16 h[2]; unsigned int u; } t;
    t.h[0] = (__bf16)a; t.h[1] = (__bf16)b;
    return t.u;
}

// async global->LDS, 16B per lane (LDS dest = wave-uniform base + lane*16)
static __device__ inline void gload16(const void* g, void* l) {
    __builtin_amdgcn_global_load_lds(
        (const __attribute__((address_space(1))) unsigned int*)g,
        (__attribute__((address_space(3))) unsigned int*)l, 16, 0, 0);
}

// ---------------------------------------------------------------------------
// Kernel 1: RMSNorm over channel axis; 64 pixels/block, 4 channel-groups.
// Output xnb is bf16 TRANSPOSED [p][c] (rows of 256 c = 512B, contiguous) so
// the MFMA QKV GEMM can DMA it directly as its B operand.
// ---------------------------------------------------------------------------
__global__ __launch_bounds__(256) void rmsnorm_kernel(const float* __restrict__ x,
                                                      const float* __restrict__ gamma,
                                                      unsigned short* __restrict__ xnb) {
    int p = blockIdx.x * 64 + (threadIdx.x & 63);
    int g = threadIdx.x >> 6;           // 0..3 channel group
    float ss = 0.f;
    for (int c = g * 64; c < g * 64 + 64; ++c) {
        float v = x[c * SPAT + p];
        ss += v * v;
    }
    __shared__ float red[4][64];
    red[g][threadIdx.x & 63] = ss;
    __syncthreads();
    int lp = threadIdx.x & 63;
    float tot = red[0][lp] + red[1][lp] + red[2][lp] + red[3][lp];
    float inv = rsqrtf(tot) * 16.0f;    // * sqrt(256)/norm
    // write xnb[p][c] for this thread's 64 channels, 8 bf16 (16B) at a time
    for (int c8 = 0; c8 < 8; ++c8) {
        int c = g * 64 + c8 * 8;
        u16x8 pk;
#pragma unroll
        for (int j = 0; j < 8; ++j)
            pk[j] = f2bf(x[(size_t)(c + j) * SPAT + p] * inv * (gamma[c + j] + 1.0f));
        *(u16x8*)&xnb[(size_t)p * C_DIM + c] = pk;
    }
}

// ---------------------------------------------------------------------------
// Kernel 2: mem_kv copy (bf16) + zero-fill pad rows/cols (ws is re-poisoned!)
// + tail: cast w_qkv (fp32) -> wb (bf16, same [3*HID][C_DIM] layout).
// kb: [h][TTOKP][64] bf16, rows 0..3 = mem k, rows 4100..4159 zero
// vtb: [h][64][TTOKP] bf16 (transposed), cols 0..3 = mem v, cols 4100.. zero
// grid: 448 blocks (65536 fixup threads + 49152 cast threads x8 elems)
// ---------------------------------------------------------------------------
__global__ __launch_bounds__(256) void fixup_kernel(const float* __restrict__ mem,
                                                    const float* __restrict__ wq,
                                                    unsigned short* __restrict__ kb,
                                                    unsigned short* __restrict__ vtb,
                                                    unsigned short* __restrict__ wb) {
    int i = blockIdx.x * 256 + threadIdx.x;
    if (i < 4096) {
        int d = i & 63, m = (i >> 6) & 3, h = (i >> 8) & 7, s = (i >> 11) & 1;
        unsigned short val = f2bf(mem[i]);
        if (s == 0) kb[(size_t)h * TTOKP * 64 + m * 64 + d] = val;
        else        vtb[((size_t)h * 64 + d) * TTOKP + m] = val;
    } else if (i < 65536) {
        int z = i - 4096;              // 0..61439
        if (z < 30720) {               // kb pad rows
            int h = z / 3840, r = z % 3840;
            int row = TTOK + r / 64, d = r % 64;
            kb[(size_t)h * TTOKP * 64 + row * 64 + d] = 0;
        } else {                       // vtb pad cols
            z -= 30720;
            int h = z / 3840, r = z % 3840;
            int d = r / 60, tcol = TTOK + r % 60;
            vtb[((size_t)h * 64 + d) * TTOKP + tcol] = 0;
        }
    } else {                           // w_qkv -> bf16 cast, 8 elems/thread
        size_t idx = (size_t)(i - 65536) * 8;   // 0 .. 393208
        float4 f0 = *(const float4*)&wq[idx];
        float4 f1 = *(const float4*)&wq[idx + 4];
        u16x8 pk;
        pk[0] = f2bf(f0.x); pk[1] = f2bf(f0.y); pk[2] = f2bf(f0.z); pk[3] = f2bf(f0.w);
        pk[4] = f2bf(f1.x); pk[5] = f2bf(f1.y); pk[6] = f2bf(f1.z); pk[7] = f2bf(f1.w);
        *(u16x8*)&wb[idx] = pk;
    }
}

// ---------------------------------------------------------------------------
// Kernel 3: QKV GEMM on MFMA (bf16 in, fp32 accum, bf16 out).
// C[o][p] = sum_c wb[o][c] * xnb[p][c].  Block = 64 o x 64 p, K = 256 in one
// shot: stage W-tile [64][256] + XnT-tile [64][256] (32KB each) via
// global_load_lds with both-sides XOR swizzle (byte ^= (row&7)<<4 within the
// 512B row), one fused vmcnt(0)+s_barrier, then 8 K-steps x 4 n-tiles of
// mfma_f32_16x16x32_bf16 per wave.  Epilogue: q/k transposed via reused LDS
// -> fully coalesced 16B stores; v stored direct (32B segments).
// q section gets folded scale 0.125*log2(e) (softmax scale + exp2 domain).
// ---------------------------------------------------------------------------
__global__ __launch_bounds__(256) void qkv_mfma(const unsigned short* __restrict__ wb,
                                                const unsigned short* __restrict__ xnb,
                                                unsigned short* __restrict__ qb,
                                                unsigned short* __restrict__ kb,
                                                unsigned short* __restrict__ vtb) {
    const int tile_p = blockIdx.x;      // 0..63
    const int tile_o = blockIdx.y;      // 0..23
    const int p0 = tile_p * 64, o0 = tile_o * 64;
    __shared__ unsigned short SW[64 * 256];   // W tile [o][c] (swizzled rows)
    __shared__ unsigned short SX[64 * 256];   // XnT tile [p][c] (swizzled rows)

    const int t = threadIdx.x;
    const int w = t >> 6, lane = t & 63;
    const int col16 = lane & 15, quad = lane >> 4;

    // --- stage both tiles: 32 chunks of 1KB each; chunk = i*4 + w ---
    {
        const char* gw = (const char*)(wb + (size_t)o0 * C_DIM);
        const char* gx = (const char*)(xnb + (size_t)p0 * C_DIM);
#pragma unroll
        for (int i = 0; i < 8; ++i) {
            int chunk = i * 4 + w;
            int row = chunk * 2 + (lane >> 5);          // 0..63
            int b = (lane & 31) * 16;                   // byte within 512B row
            int src = row * 512 + (b ^ ((row & 7) << 4));
            gload16(gw + src, (char*)SW + chunk * 1024);
            gload16(gx + src, (char*)SX + chunk * 1024);
        }
    }
    asm volatile("s_waitcnt vmcnt(0)\n\ts_barrier" ::: "memory");
    __builtin_amdgcn_sched_barrier(0);

    // --- K-loop: 8 steps of 32, 4 n-tiles ---
    const int cs = (col16 & 7) << 4;                    // read-side swizzle
    const char* swp = (const char*)SW;
    const char* sxp = (const char*)SX;
    const int arow = (w * 16 + col16) * 512;
    f32x4 acc[4];
#pragma unroll
    for (int n = 0; n < 4; ++n) acc[n] = (f32x4){0.f, 0.f, 0.f, 0.f};
#pragma unroll
    for (int kk = 0; kk < 8; ++kk) {
        int ko = (kk * 64 + quad * 16) ^ cs;
        bf16x8 a = ldb8((const unsigned short*)(swp + arow + ko));
#pragma unroll
        for (int n = 0; n < 4; ++n) {
            bf16x8 b = ldb8((const unsigned short*)(sxp + (n * 16 + col16) * 512 + ko));
            acc[n] = __builtin_amdgcn_mfma_f32_16x16x32_bf16(a, b, acc[n], 0, 0, 0);
        }
    }

    // --- epilogue ---
    const int sec = tile_o >> 3, h = tile_o & 7;
    if (sec < 2) {
        const float qsc = (sec == 0) ? 0.125f * 1.4426950408889634f : 1.0f;
        unsigned short* Ot = SW;                        // reuse, pitch PSP=72
        __syncthreads();                                // all MFMA LDS reads done
#pragma unroll
        for (int n = 0; n < 4; ++n) {
            ushort4 v4 = {f2bf(acc[n][0] * qsc), f2bf(acc[n][1] * qsc),
                          f2bf(acc[n][2] * qsc), f2bf(acc[n][3] * qsc)};
            *(ushort4*)&Ot[(n * 16 + col16) * PSP + w * 16 + quad * 4] = v4;
        }
        __syncthreads();
        int prow = t >> 2, dseg = t & 3;
        u16x8 va = *(u16x8*)&Ot[prow * PSP + dseg * 16];
        u16x8 vb = *(u16x8*)&Ot[prow * PSP + dseg * 16 + 8];
        unsigned short* dst = (sec == 0)
            ? qb + (size_t)h * SPAT * 64 + (size_t)(p0 + prow) * 64
            : kb + (size_t)h * TTOKP * 64 + (size_t)(MEMTOK + p0 + prow) * 64;
        *(u16x8*)&dst[dseg * 16] = va;
        *(u16x8*)&dst[dseg * 16 + 8] = vb;
    } else {   // v: direct store to vtb[h][d][t] (32B-segment coalesced)
        unsigned short* dst = vtb + (size_t)h * 64 * TTOKP;
#pragma unroll
        for (int n = 0; n < 4; ++n) {
            int tcol = MEMTOK + p0 + n * 16 + col16;
#pragma unroll
            for (int r = 0; r < 4; ++r)
                dst[(size_t)(w * 16 + quad * 4 + r) * TTOKP + tcol] = f2bf(acc[n][r]);
        }
    }
}

// ---------------------------------------------------------------------------
// Kernel 4: flash attention, bf16 MFMA (16x16x32), fp32 accum.  (unchanged)
// Swapped-operand form: QK^T computed as mfma(K,Q) -> S^T (lane owns one q-row),
// PV computed as mfma(V^T,P) -> O^T[d][q]. Softmax reduce = 15 local fmax + 2 shfl.
// K/V tiles DOUBLE-buffered via global_load_lds. STAGE(t+1) at the TOP of each
// tile; one FUSED "s_waitcnt vmcnt(0); s_barrier" at the BOTTOM.
// Output ob is [h][64 d][4096 p] fp32.
// ---------------------------------------------------------------------------
__global__ __launch_bounds__(256) void attn_mfma(const unsigned short* __restrict__ qb,
                                                 const unsigned short* __restrict__ kb,
                                                 const unsigned short* __restrict__ vtb,
                                                 float* __restrict__ ob) {
    const int h  = blockIdx.x & 7;           // head = bid%8 -> all blocks of a head on one XCD
    const int p0 = (blockIdx.x >> 3) * 64;

    __shared__ unsigned short Ks0[64 * 64], Ks1[64 * 64];
    __shared__ unsigned short Vs0[64 * 64], Vs1[64 * 64];
    __shared__ __bf16 Psb[4 * 16 * PSP];

    const int t = threadIdx.x;
    const int w = t >> 6;
    const int lane = t & 63;
    const int col16 = lane & 15;
    const int quad = lane >> 4;

    const unsigned short* qh = qb + (size_t)h * SPAT * 64;
    const char* khb = (const char*)(kb + (size_t)h * TTOKP * 64);
    const char* vhb = (const char*)(vtb + (size_t)h * 64 * TTOKP);
    float* ohd = ob + (size_t)h * 64 * SPAT;

    const int srow = w * 16 + (lane >> 3);                       // chunk i adds +8
    const int scol = (((lane & 7) ^ ((lane >> 3) & 7)) << 4);

    const int cswz = col16 & 7;
    const int sw0 = ((quad ^ cswz) << 4);
    const int sw1 = (((quad + 4) ^ cswz) << 4);
    const int rB = col16 * 128;

    bf16x8 aq0 = ldb8(&qh[(size_t)(p0 + w * 16 + col16) * 64 + quad * 8]);
    bf16x8 aq1 = ldb8(&qh[(size_t)(p0 + w * 16 + col16) * 64 + 32 + quad * 8]);

    float m_i = -1e30f, l_i = 0.f;
    f32x4 Oa[4];
#pragma unroll
    for (int n = 0; n < 4; ++n) Oa[n] = (f32x4){0.f, 0.f, 0.f, 0.f};

    __bf16* pw = &Psb[(w * 16 + col16) * PSP];
    const unsigned short* pr = (const unsigned short*)pw;

    auto STAGE = [&](int tb, unsigned short* Kd, unsigned short* Vd) {
        size_t kro = ((size_t)tb * 64 + srow) * 128 + scol;
        gload16(khb + kro,        (char*)Kd + w * 2048);
        gload16(khb + kro + 1024, (char*)Kd + w * 2048 + 1024);        // rows +8
        size_t vro = (size_t)srow * (TTOKP * 2) + (size_t)tb * 128 + scol;
        gload16(vhb + vro,                           (char*)Vd + w * 2048);
        gload16(vhb + vro + (size_t)8 * (TTOKP * 2), (char*)Vd + w * 2048 + 1024);
    };

    auto STEP = [&](int tile, const unsigned short* Kc_, const unsigned short* Vc_,
                    unsigned short* Ksn, unsigned short* Vsn, bool stage, bool last) {
        if (stage) STAGE(tile + 1, Ksn, Vsn);

        const char* Kc = (const char*)Kc_;
        const char* Vc = (const char*)Vc_;

        f32x4 sv[4];
#pragma unroll
        for (int n = 0; n < 4; ++n) {
            sv[n] = (f32x4){0.f, 0.f, 0.f, 0.f};
            bf16x8 bk0 = ldb8((const unsigned short*)(Kc + n * 2048 + rB + sw0));
            bf16x8 bk1 = ldb8((const unsigned short*)(Kc + n * 2048 + rB + sw1));
            sv[n] = __builtin_amdgcn_mfma_f32_16x16x32_bf16(bk0, aq0, sv[n], 0, 0, 0);
            sv[n] = __builtin_amdgcn_mfma_f32_16x16x32_bf16(bk1, aq1, sv[n], 0, 0, 0);
        }

        if (last) {   // tile 64: only keys 0..3 valid (n==0 && quad==0)
#pragma unroll
            for (int n = 0; n < 4; ++n)
#pragma unroll
                for (int r = 0; r < 4; ++r)
                    if ((n | quad) != 0) sv[n][r] = -1e30f;
        }

        float rm = fmaxf(
            fmaxf(fmaxf(fmaxf(sv[0][0], sv[0][1]), fmaxf(sv[0][2], sv[0][3])),
                  fmaxf(fmaxf(sv[1][0], sv[1][1]), fmaxf(sv[1][2], sv[1][3]))),
            fmaxf(fmaxf(fmaxf(sv[2][0], sv[2][1]), fmaxf(sv[2][2], sv[2][3])),
                  fmaxf(fmaxf(sv[3][0], sv[3][1]), fmaxf(sv[3][2], sv[3][3]))));
        rm = fmaxf(rm, __shfl_xor(rm, 16, 64));
        rm = fmaxf(rm, __shfl_xor(rm, 32, 64));

        float mn = fmaxf(m_i, rm);
        float al = __builtin_amdgcn_exp2f(m_i - mn);
        m_i = mn;

        float rs = 0.f;
#pragma unroll
        for (int n = 0; n < 4; ++n) {
            float e0 = __builtin_amdgcn_exp2f(sv[n][0] - mn);
            float e1 = __builtin_amdgcn_exp2f(sv[n][1] - mn);
            float e2 = __builtin_amdgcn_exp2f(sv[n][2] - mn);
            float e3 = __builtin_amdgcn_exp2f(sv[n][3] - mn);
            rs += (e0 + e1) + (e2 + e3);
            *(unsigned int*)&pw[n * 16 + quad * 4]     = pkbf(e0, e1);
            *(unsigned int*)&pw[n * 16 + quad * 4 + 2] = pkbf(e2, e3);
        }
        rs += __shfl_xor(rs, 16, 64);
        rs += __shfl_xor(rs, 32, 64);
        l_i = l_i * al + rs;

#pragma unroll
        for (int n = 0; n < 4; ++n) {
            Oa[n][0] *= al; Oa[n][1] *= al; Oa[n][2] *= al; Oa[n][3] *= al;
        }

        bf16x8 pa0 = ldb8(pr + quad * 8);
        bf16x8 pa1 = ldb8(pr + 32 + quad * 8);

#pragma unroll
        for (int n = 0; n < 4; ++n) {
            bf16x8 bv0 = ldb8((const unsigned short*)(Vc + n * 2048 + rB + sw0));
            bf16x8 bv1 = ldb8((const unsigned short*)(Vc + n * 2048 + rB + sw1));
            Oa[n] = __builtin_amdgcn_mfma_f32_16x16x32_bf16(bv0, pa0, Oa[n], 0, 0, 0);
            Oa[n] = __builtin_amdgcn_mfma_f32_16x16x32_bf16(bv1, pa1, Oa[n], 0, 0, 0);
        }

        if (!last) {
            asm volatile("s_waitcnt vmcnt(0)\n\ts_barrier" ::: "memory");
            __builtin_amdgcn_sched_barrier(0);
        }
    };

    STAGE(0, Ks0, Vs0);
    asm volatile("s_waitcnt vmcnt(0)\n\ts_barrier" ::: "memory");
    __builtin_amdgcn_sched_barrier(0);

    for (int b = 0; b < 64; b += 2) {
        STEP(b,     Ks0, Vs0, Ks1, Vs1, true, false);
        STEP(b + 1, Ks1, Vs1, Ks0, Vs0, true, false);
    }
    STEP(64, Ks0, Vs0, Ks1, Vs1, false, true);

    float inv = 1.0f / l_i;
    int p = p0 + w * 16 + col16;
#pragma unroll
    for (int n = 0; n < 4; ++n)
#pragma unroll
        for (int r = 0; r < 4; ++r)
            ohd[(size_t)(n * 16 + quad * 4 + r) * SPAT + p] = Oa[n][r] * inv;
}

// ---------------------------------------------------------------------------
// Kernel 5: out projection (fp32): out[oc,p] = sum_{h,d} w_out[oc,h*64+d]*ob[h][d][p]
// ob is [h][d][p] -> B-tile load is a plain coalesced row copy.  (unchanged)
// ---------------------------------------------------------------------------
__global__ __launch_bounds__(256) void out_gemm(const float* __restrict__ w,
                                                const float* __restrict__ ob,
                                                float* __restrict__ out) {
    int p0 = blockIdx.x * 64;
    int o0 = blockIdx.y * 64;
    __shared__ float at[16][68];
    __shared__ float bt[16][68];
    int t = threadIdx.x;
    int tx = t & 15, ty = t >> 4;
    float acc[4][4];
#pragma unroll
    for (int i = 0; i < 4; ++i)
#pragma unroll
        for (int j = 0; j < 4; ++j) acc[i][j] = 0.f;

    for (int c0 = 0; c0 < HID; c0 += 16) {
        int hh = c0 >> 6;
        int d0 = c0 & 63;
        __syncthreads();
        {
            int lo = t >> 2, lc4 = (t & 3) * 4;
            float4 wv = *(const float4*)&w[(size_t)(o0 + lo) * HID + c0 + lc4];
            at[lc4 + 0][lo] = wv.x; at[lc4 + 1][lo] = wv.y;
            at[lc4 + 2][lo] = wv.z; at[lc4 + 3][lo] = wv.w;
        }
        {
            int lc = t >> 4, lp4 = (t & 15) * 4;
            *(float4*)&bt[lc][lp4] =
                *(const float4*)&ob[((size_t)hh * 64 + d0 + lc) * SPAT + p0 + lp4];
        }
        __syncthreads();
#pragma unroll
        for (int lc = 0; lc < 16; ++lc) {
            float4 a4 = *(float4*)&at[lc][tx * 4];
            float4 b4 = *(float4*)&bt[lc][ty * 4];
            float av[4] = {a4.x, a4.y, a4.z, a4.w};
            float bv[4] = {b4.x, b4.y, b4.z, b4.w};
#pragma unroll
            for (int i = 0; i < 4; ++i)
#pragma unroll
                for (int j = 0; j < 4; ++j) acc[i][j] += av[i] * bv[j];
        }
    }
#pragma unroll
    for (int i = 0; i < 4; ++i) {
        float4 val = {acc[i][0], acc[i][1], acc[i][2], acc[i][3]};
        *(float4*)&out[(size_t)(o0 + tx * 4 + i) * SPAT + p0 + ty * 4] = val;
    }
}

// ---------------------------------------------------------------------------
// Launch
// ---------------------------------------------------------------------------
extern "C" void kernel_launch(void* const* d_in, const int* in_sizes, int n_in,
                              void* d_out, int out_size, void* d_ws, size_t ws_size,
                              hipStream_t stream) {
    const float* x      = (const float*)d_in[0];
    const float* gamma  = (const float*)d_in[1];
    const float* mem_kv = (const float*)d_in[2];
    const float* w_qkv  = (const float*)d_in[3];
    const float* w_out  = (const float*)d_in[4];
    float* out = (float*)d_out;

    // workspace: xnb(bf16 [p][c]) | wb(bf16) | qb | kb | vtb | ob(f32)  ~23.6 MB
    unsigned short* xnb = (unsigned short*)d_ws;
    unsigned short* wb  = xnb + (size_t)SPAT * C_DIM;
    unsigned short* qb  = wb + (size_t)3 * HID * C_DIM;
    unsigned short* kb  = qb + (size_t)HEADS_N * SPAT * DHEAD;
    unsigned short* vtb = kb + (size_t)HEADS_N * TTOKP * DHEAD;
    float* ob = (float*)(vtb + (size_t)HEADS_N * DHEAD * TTOKP);

    rmsnorm_kernel<<<dim3(64), 256, 0, stream>>>(x, gamma, xnb);
    fixup_kernel<<<dim3(448), 256, 0, stream>>>(mem_kv, w_qkv, kb, vtb, wb);
    qkv_mfma<<<dim3(64, 24), 256, 0, stream>>>(wb, xnb, qb, kb, vtb);
    attn_mfma<<<dim3(512), 256, 0, stream>>>(qb, kb, vtb, ob);
    out_gemm<<<dim3(64, 4), 256, 0, stream>>>(w_out, ob, out);
}

// Round 4
// 166.964 us; speedup vs baseline: 1.7285x; 1.2328x over previous
//
#include <hip/hip_runtime.h>
#include <hip/hip_bf16.h>
#include <math.h>

// Problem constants
#define C_DIM 256      // channels
#define SPAT 4096      // h*w = 64*64
#define HEADS_N 8
#define DHEAD 64
#define MEMTOK 4
#define TTOK 4100      // MEMTOK + SPAT
#define TTOKP 4160     // padded to 65 tiles of 64
#define HID 512        // HEADS_N * DHEAD
#define PSP 72         // Ps LDS row pitch in bf16 elems (144 B; keeps 16B align for b128)

typedef __bf16 bf16x8 __attribute__((ext_vector_type(8)));
typedef unsigned short u16x8 __attribute__((ext_vector_type(8)));
typedef float f32x4 __attribute__((ext_vector_type(4)));

static __device__ inline unsigned short f2bf(float f) {  // RNE f32->bf16
    unsigned int u = __float_as_uint(f);
    u += 0x7fffu + ((u >> 16) & 1u);
    return (unsigned short)(u >> 16);
}

static __device__ inline bf16x8 ldb8(const unsigned short* p) {
    union { u16x8 u; bf16x8 b; } t;
    t.u = *(const u16x8*)p;
    return t.b;
}

static __device__ inline unsigned int pkbf(float a, float b) {  // packed bf16 pair
    union { __bf16 h[2]; unsigned int u; } t;
    t.h[0] = (__bf16)a; t.h[1] = (__bf16)b;
    return t.u;
}

// async global->LDS, 16B per lane (LDS dest = wave-uniform base + lane*16)
static __device__ inline void gload16(const void* g, void* l) {
    __builtin_amdgcn_global_load_lds(
        (const __attribute__((address_space(1))) unsigned int*)g,
        (__attribute__((address_space(3))) unsigned int*)l, 16, 0, 0);
}

// ---------------------------------------------------------------------------
// Kernel 1: prep — everything elementwise, one launch, 832 blocks:
//  A (bid 0..255):   x [c][p] fp32 -> xb [p][c] bf16 (LDS 64x64 transpose)
//  B (bid 256..319): spb[p] = 16 * rsqrt(sum_c x^2)   (fp32, exact RMSNorm)
//  C (bid 320..511): wb  = bf16(w_qkv * (gamma[c]+1))  (gamma folded into W)
//  D (bid 512..575): wob = bf16(w_out)
//  E (bid 576..831): mem_kv placement + kb/vtb zero pads (ws re-poisoned!)
// ---------------------------------------------------------------------------
__global__ __launch_bounds__(256) void prep_kernel(
    const float* __restrict__ x, const float* __restrict__ gamma,
    const float* __restrict__ mem, const float* __restrict__ wq,
    const float* __restrict__ wo,
    unsigned short* __restrict__ xb, float* __restrict__ spb,
    unsigned short* __restrict__ wb, unsigned short* __restrict__ wob,
    unsigned short* __restrict__ kb, unsigned short* __restrict__ vtb) {
    __shared__ float XT[64][65];
    __shared__ float red[4][64];
    const int bid = blockIdx.x;
    const int t = threadIdx.x;
    if (bid < 256) {              // A: transpose-cast x
        int p0 = (bid & 63) * 64, c0 = (bid >> 6) * 64;
#pragma unroll
        for (int i = 0; i < 4; ++i) {
            int cl = i * 16 + (t >> 4), p4 = (t & 15) * 4;
            *(float4*)&XT[cl][p4] = *(const float4*)&x[(size_t)(c0 + cl) * SPAT + p0 + p4];
        }
        __syncthreads();
        int pl = t >> 2, cs = (t & 3) * 16;
        u16x8 a, b;
#pragma unroll
        for (int j = 0; j < 8; ++j) a[j] = f2bf(XT[cs + j][pl]);
#pragma unroll
        for (int j = 0; j < 8; ++j) b[j] = f2bf(XT[cs + 8 + j][pl]);
        *(u16x8*)&xb[(size_t)(p0 + pl) * C_DIM + c0 + cs] = a;
        *(u16x8*)&xb[(size_t)(p0 + pl) * C_DIM + c0 + cs + 8] = b;
    } else if (bid < 320) {       // B: norms
        int p = (bid - 256) * 64 + (t & 63);
        int g = t >> 6;
        float ss = 0.f;
        for (int c = g * 64; c < g * 64 + 64; ++c) {
            float v = x[(size_t)c * SPAT + p];
            ss += v * v;
        }
        red[g][t & 63] = ss;
        __syncthreads();
        if (g == 0) {
            int lp = t & 63;
            float tot = red[0][lp] + red[1][lp] + red[2][lp] + red[3][lp];
            spb[p] = rsqrtf(tot) * 16.0f;
        }
    } else if (bid < 512) {       // C: wb = bf16(wq * (gamma+1)), 8 elems/thread
        size_t idx = ((size_t)(bid - 320) * 256 + t) * 8;
        int c0 = (int)(idx & 255);
        float4 f0 = *(const float4*)&wq[idx];
        float4 f1 = *(const float4*)&wq[idx + 4];
        float4 g0 = *(const float4*)&gamma[c0];
        float4 g1 = *(const float4*)&gamma[c0 + 4];
        u16x8 pk;
        pk[0] = f2bf(f0.x * (g0.x + 1.f)); pk[1] = f2bf(f0.y * (g0.y + 1.f));
        pk[2] = f2bf(f0.z * (g0.z + 1.f)); pk[3] = f2bf(f0.w * (g0.w + 1.f));
        pk[4] = f2bf(f1.x * (g1.x + 1.f)); pk[5] = f2bf(f1.y * (g1.y + 1.f));
        pk[6] = f2bf(f1.z * (g1.z + 1.f)); pk[7] = f2bf(f1.w * (g1.w + 1.f));
        *(u16x8*)&wb[idx] = pk;
    } else if (bid < 576) {       // D: wob = bf16(wo)
        size_t idx = ((size_t)(bid - 512) * 256 + t) * 8;
        float4 f0 = *(const float4*)&wo[idx];
        float4 f1 = *(const float4*)&wo[idx + 4];
        u16x8 pk;
        pk[0] = f2bf(f0.x); pk[1] = f2bf(f0.y); pk[2] = f2bf(f0.z); pk[3] = f2bf(f0.w);
        pk[4] = f2bf(f1.x); pk[5] = f2bf(f1.y); pk[6] = f2bf(f1.z); pk[7] = f2bf(f1.w);
        *(u16x8*)&wob[idx] = pk;
    } else {                      // E: mem_kv + zero pads
        int i = (bid - 576) * 256 + t;
        if (i < 4096) {
            int d = i & 63, m = (i >> 6) & 3, h = (i >> 8) & 7, s = (i >> 11) & 1;
            unsigned short val = f2bf(mem[i]);
            if (s == 0) kb[(size_t)h * TTOKP * 64 + m * 64 + d] = val;
            else        vtb[((size_t)h * 64 + d) * TTOKP + m] = val;
        } else {
            int z = i - 4096;              // 0..61439
            if (z < 30720) {               // kb pad rows
                int h = z / 3840, r = z % 3840;
                int row = TTOK + r / 64, d = r % 64;
                kb[(size_t)h * TTOKP * 64 + row * 64 + d] = 0;
            } else {                       // vtb pad cols
                z -= 30720;
                int h = z / 3840, r = z % 3840;
                int d = r / 60, tcol = TTOK + r % 60;
                vtb[((size_t)h * 64 + d) * TTOKP + tcol] = 0;
            }
        }
    }
}

// ---------------------------------------------------------------------------
// Kernel 2: QKV GEMM on MFMA (bf16 in, fp32 accum, bf16 out).
// C[o][p] = sp[p] * sum_c wb[o][c] * xb[p][c]   (RMSNorm scale folded into
// epilogue; gamma already folded into wb).  Same staging/swizzle template as
// before.  q gets additional 0.125*log2(e).
// ---------------------------------------------------------------------------
__global__ __launch_bounds__(256) void qkv_mfma(const unsigned short* __restrict__ wb,
                                                const unsigned short* __restrict__ xb,
                                                const float* __restrict__ spb,
                                                unsigned short* __restrict__ qb,
                                                unsigned short* __restrict__ kb,
                                                unsigned short* __restrict__ vtb) {
    const int tile_p = blockIdx.x;      // 0..63
    const int tile_o = blockIdx.y;      // 0..23
    const int p0 = tile_p * 64, o0 = tile_o * 64;
    __shared__ unsigned short SW[64 * 256];   // W tile [o][c] (swizzled rows)
    __shared__ unsigned short SX[64 * 256];   // Xb tile [p][c] (swizzled rows)

    const int t = threadIdx.x;
    const int w = t >> 6, lane = t & 63;
    const int col16 = lane & 15, quad = lane >> 4;

    {
        const char* gw = (const char*)(wb + (size_t)o0 * C_DIM);
        const char* gx = (const char*)(xb + (size_t)p0 * C_DIM);
#pragma unroll
        for (int i = 0; i < 8; ++i) {
            int chunk = i * 4 + w;
            int row = chunk * 2 + (lane >> 5);          // 0..63
            int b = (lane & 31) * 16;                   // byte within 512B row
            int src = row * 512 + (b ^ ((row & 7) << 4));
            gload16(gw + src, (char*)SW + chunk * 1024);
            gload16(gx + src, (char*)SX + chunk * 1024);
        }
    }
    asm volatile("s_waitcnt vmcnt(0)\n\ts_barrier" ::: "memory");
    __builtin_amdgcn_sched_barrier(0);

    const int cs = (col16 & 7) << 4;                    // read-side swizzle
    const char* swp = (const char*)SW;
    const char* sxp = (const char*)SX;
    const int arow = (w * 16 + col16) * 512;
    f32x4 acc[4];
#pragma unroll
    for (int n = 0; n < 4; ++n) acc[n] = (f32x4){0.f, 0.f, 0.f, 0.f};
#pragma unroll
    for (int kk = 0; kk < 8; ++kk) {
        int ko = (kk * 64 + quad * 16) ^ cs;
        bf16x8 a = ldb8((const unsigned short*)(swp + arow + ko));
#pragma unroll
        for (int n = 0; n < 4; ++n) {
            bf16x8 b = ldb8((const unsigned short*)(sxp + (n * 16 + col16) * 512 + ko));
            acc[n] = __builtin_amdgcn_mfma_f32_16x16x32_bf16(a, b, acc[n], 0, 0, 0);
        }
    }

    // --- epilogue: apply sp[p] (and QSC for q), store ---
    float spv[4];
#pragma unroll
    for (int n = 0; n < 4; ++n) spv[n] = spb[p0 + n * 16 + col16];

    const int sec = tile_o >> 3, h = tile_o & 7;
    if (sec < 2) {
        const float qsc = (sec == 0) ? 0.125f * 1.4426950408889634f : 1.0f;
        unsigned short* Ot = SW;                        // reuse, pitch PSP=72
        __syncthreads();                                // all MFMA LDS reads done
#pragma unroll
        for (int n = 0; n < 4; ++n) {
            float s = qsc * spv[n];
            ushort4 v4 = {f2bf(acc[n][0] * s), f2bf(acc[n][1] * s),
                          f2bf(acc[n][2] * s), f2bf(acc[n][3] * s)};
            *(ushort4*)&Ot[(n * 16 + col16) * PSP + w * 16 + quad * 4] = v4;
        }
        __syncthreads();
        int prow = t >> 2, dseg = t & 3;
        u16x8 va = *(u16x8*)&Ot[prow * PSP + dseg * 16];
        u16x8 vb = *(u16x8*)&Ot[prow * PSP + dseg * 16 + 8];
        unsigned short* dst = (sec == 0)
            ? qb + (size_t)h * SPAT * 64 + (size_t)(p0 + prow) * 64
            : kb + (size_t)h * TTOKP * 64 + (size_t)(MEMTOK + p0 + prow) * 64;
        *(u16x8*)&dst[dseg * 16] = va;
        *(u16x8*)&dst[dseg * 16 + 8] = vb;
    } else {   // v: direct store to vtb[h][d][t] (32B-segment coalesced)
        unsigned short* dst = vtb + (size_t)h * 64 * TTOKP;
#pragma unroll
        for (int n = 0; n < 4; ++n) {
            int tcol = MEMTOK + p0 + n * 16 + col16;
            float s = spv[n];
#pragma unroll
            for (int r = 0; r < 4; ++r)
                dst[(size_t)(w * 16 + quad * 4 + r) * TTOKP + tcol] = f2bf(acc[n][r] * s);
        }
    }
}

// ---------------------------------------------------------------------------
// Kernel 3: flash attention, bf16 MFMA (16x16x32), fp32 accum.
// Core identical to Round-2 (verified twice).  Epilogue now writes bf16
// obb[p][h*64+d] via per-wave LDS transpose (coalesced 128B segments) —
// the exact B-operand layout for the MFMA out-projection.
// ---------------------------------------------------------------------------
__global__ __launch_bounds__(256) void attn_mfma(const unsigned short* __restrict__ qb,
                                                 const unsigned short* __restrict__ kb,
                                                 const unsigned short* __restrict__ vtb,
                                                 unsigned short* __restrict__ obb) {
    const int h  = blockIdx.x & 7;           // head = bid%8 -> all blocks of a head on one XCD
    const int p0 = (blockIdx.x >> 3) * 64;

    __shared__ unsigned short Ks0[64 * 64], Ks1[64 * 64];
    __shared__ unsigned short Vs0[64 * 64], Vs1[64 * 64];
    __shared__ __bf16 Psb[4 * 16 * PSP];

    const int t = threadIdx.x;
    const int w = t >> 6;
    const int lane = t & 63;
    const int col16 = lane & 15;
    const int quad = lane >> 4;

    const unsigned short* qh = qb + (size_t)h * SPAT * 64;
    const char* khb = (const char*)(kb + (size_t)h * TTOKP * 64);
    const char* vhb = (const char*)(vtb + (size_t)h * 64 * TTOKP);

    const int srow = w * 16 + (lane >> 3);                       // chunk i adds +8
    const int scol = (((lane & 7) ^ ((lane >> 3) & 7)) << 4);

    const int cswz = col16 & 7;
    const int sw0 = ((quad ^ cswz) << 4);
    const int sw1 = (((quad + 4) ^ cswz) << 4);
    const int rB = col16 * 128;

    bf16x8 aq0 = ldb8(&qh[(size_t)(p0 + w * 16 + col16) * 64 + quad * 8]);
    bf16x8 aq1 = ldb8(&qh[(size_t)(p0 + w * 16 + col16) * 64 + 32 + quad * 8]);

    float m_i = -1e30f, l_i = 0.f;
    f32x4 Oa[4];
#pragma unroll
    for (int n = 0; n < 4; ++n) Oa[n] = (f32x4){0.f, 0.f, 0.f, 0.f};

    __bf16* pw = &Psb[(w * 16 + col16) * PSP];
    const unsigned short* pr = (const unsigned short*)pw;

    auto STAGE = [&](int tb, unsigned short* Kd, unsigned short* Vd) {
        size_t kro = ((size_t)tb * 64 + srow) * 128 + scol;
        gload16(khb + kro,        (char*)Kd + w * 2048);
        gload16(khb + kro + 1024, (char*)Kd + w * 2048 + 1024);        // rows +8
        size_t vro = (size_t)srow * (TTOKP * 2) + (size_t)tb * 128 + scol;
        gload16(vhb + vro,                           (char*)Vd + w * 2048);
        gload16(vhb + vro + (size_t)8 * (TTOKP * 2), (char*)Vd + w * 2048 + 1024);
    };

    auto STEP = [&](int tile, const unsigned short* Kc_, const unsigned short* Vc_,
                    unsigned short* Ksn, unsigned short* Vsn, bool stage, bool last) {
        if (stage) STAGE(tile + 1, Ksn, Vsn);

        const char* Kc = (const char*)Kc_;
        const char* Vc = (const char*)Vc_;

        f32x4 sv[4];
#pragma unroll
        for (int n = 0; n < 4; ++n) {
            sv[n] = (f32x4){0.f, 0.f, 0.f, 0.f};
            bf16x8 bk0 = ldb8((const unsigned short*)(Kc + n * 2048 + rB + sw0));
            bf16x8 bk1 = ldb8((const unsigned short*)(Kc + n * 2048 + rB + sw1));
            sv[n] = __builtin_amdgcn_mfma_f32_16x16x32_bf16(bk0, aq0, sv[n], 0, 0, 0);
            sv[n] = __builtin_amdgcn_mfma_f32_16x16x32_bf16(bk1, aq1, sv[n], 0, 0, 0);
        }

        if (last) {   // tile 64: only keys 0..3 valid (n==0 && quad==0)
#pragma unroll
            for (int n = 0; n < 4; ++n)
#pragma unroll
                for (int r = 0; r < 4; ++r)
                    if ((n | quad) != 0) sv[n][r] = -1e30f;
        }

        float rm = fmaxf(
            fmaxf(fmaxf(fmaxf(sv[0][0], sv[0][1]), fmaxf(sv[0][2], sv[0][3])),
                  fmaxf(fmaxf(sv[1][0], sv[1][1]), fmaxf(sv[1][2], sv[1][3]))),
            fmaxf(fmaxf(fmaxf(sv[2][0], sv[2][1]), fmaxf(sv[2][2], sv[2][3])),
                  fmaxf(fmaxf(sv[3][0], sv[3][1]), fmaxf(sv[3][2], sv[3][3]))));
        rm = fmaxf(rm, __shfl_xor(rm, 16, 64));
        rm = fmaxf(rm, __shfl_xor(rm, 32, 64));

        float mn = fmaxf(m_i, rm);
        float al = __builtin_amdgcn_exp2f(m_i - mn);
        m_i = mn;

        float rs = 0.f;
#pragma unroll
        for (int n = 0; n < 4; ++n) {
            float e0 = __builtin_amdgcn_exp2f(sv[n][0] - mn);
            float e1 = __builtin_amdgcn_exp2f(sv[n][1] - mn);
            float e2 = __builtin_amdgcn_exp2f(sv[n][2] - mn);
            float e3 = __builtin_amdgcn_exp2f(sv[n][3] - mn);
            rs += (e0 + e1) + (e2 + e3);
            *(unsigned int*)&pw[n * 16 + quad * 4]     = pkbf(e0, e1);
            *(unsigned int*)&pw[n * 16 + quad * 4 + 2] = pkbf(e2, e3);
        }
        rs += __shfl_xor(rs, 16, 64);
        rs += __shfl_xor(rs, 32, 64);
        l_i = l_i * al + rs;

#pragma unroll
        for (int n = 0; n < 4; ++n) {
            Oa[n][0] *= al; Oa[n][1] *= al; Oa[n][2] *= al; Oa[n][3] *= al;
        }

        bf16x8 pa0 = ldb8(pr + quad * 8);
        bf16x8 pa1 = ldb8(pr + 32 + quad * 8);

#pragma unroll
        for (int n = 0; n < 4; ++n) {
            bf16x8 bv0 = ldb8((const unsigned short*)(Vc + n * 2048 + rB + sw0));
            bf16x8 bv1 = ldb8((const unsigned short*)(Vc + n * 2048 + rB + sw1));
            Oa[n] = __builtin_amdgcn_mfma_f32_16x16x32_bf16(bv0, pa0, Oa[n], 0, 0, 0);
            Oa[n] = __builtin_amdgcn_mfma_f32_16x16x32_bf16(bv1, pa1, Oa[n], 0, 0, 0);
        }

        if (!last) {
            asm volatile("s_waitcnt vmcnt(0)\n\ts_barrier" ::: "memory");
            __builtin_amdgcn_sched_barrier(0);
        }
    };

    STAGE(0, Ks0, Vs0);
    asm volatile("s_waitcnt vmcnt(0)\n\ts_barrier" ::: "memory");
    __builtin_amdgcn_sched_barrier(0);

    for (int b = 0; b < 64; b += 2) {
        STEP(b,     Ks0, Vs0, Ks1, Vs1, true, false);
        STEP(b + 1, Ks1, Vs1, Ks0, Vs0, true, false);
    }
    STEP(64, Ks0, Vs0, Ks1, Vs1, false, true);

    // epilogue: O^T/l -> bf16, per-wave LDS transpose -> obb[p][h*64+d]
    float inv = 1.0f / l_i;
    __bf16* ot = &Psb[(size_t)w * 16 * PSP];   // per-wave 16-row region (reuse)
#pragma unroll
    for (int n = 0; n < 4; ++n) {
        *(unsigned int*)&ot[col16 * PSP + n * 16 + quad * 4] =
            pkbf(Oa[n][0] * inv, Oa[n][1] * inv);
        *(unsigned int*)&ot[col16 * PSP + n * 16 + quad * 4 + 2] =
            pkbf(Oa[n][2] * inv, Oa[n][3] * inv);
    }
    int q2 = lane >> 2, dseg = (lane & 3) * 16;
    const unsigned short* otr = (const unsigned short*)ot;
    u16x8 o0v = *(const u16x8*)&otr[q2 * PSP + dseg];
    u16x8 o1v = *(const u16x8*)&otr[q2 * PSP + dseg + 8];
    unsigned short* dst = obb + (size_t)(p0 + w * 16 + q2) * HID + h * DHEAD + dseg;
    *(u16x8*)&dst[0] = o0v;
    *(u16x8*)&dst[8] = o1v;
}

// ---------------------------------------------------------------------------
// Kernel 4: out projection on MFMA (bf16 in, fp32 accum, fp32 out).
// out[o][p] = sum_hd wob[o][hd] * obb[p][hd].  Two K=256 stages (64KB LDS),
// same staging/swizzle template (global rows are 1KB; swizzle within 512B
// half-rows).  Epilogue: per-wave LDS transpose -> coalesced float4 stores.
// ---------------------------------------------------------------------------
__global__ __launch_bounds__(256) void out_mfma(const unsigned short* __restrict__ wob,
                                                const unsigned short* __restrict__ obb,
                                                float* __restrict__ out) {
    const int p0 = blockIdx.x * 64;   // 64 p-tiles
    const int o0 = blockIdx.y * 64;   // 4 o-tiles
    __shared__ unsigned short SW[64 * 256];   // [o][256 k] half
    __shared__ unsigned short SO[64 * 256];   // [p][256 k] half
    __shared__ float OT[4][16 * 68];          // per-wave [16 o][64 p], pitch 68

    const int t = threadIdx.x;
    const int w = t >> 6, lane = t & 63;
    const int col16 = lane & 15, quad = lane >> 4;
    const int cs = (col16 & 7) << 4;
    const int arow = (w * 16 + col16) * 512;

    f32x4 acc[4];
#pragma unroll
    for (int n = 0; n < 4; ++n) acc[n] = (f32x4){0.f, 0.f, 0.f, 0.f};

#pragma unroll
    for (int ks = 0; ks < 2; ++ks) {
        const char* gw = (const char*)(wob + (size_t)o0 * HID) + ks * 512;
        const char* go = (const char*)(obb + (size_t)p0 * HID) + ks * 512;
#pragma unroll
        for (int i = 0; i < 8; ++i) {
            int chunk = i * 4 + w;                      // 0..31 (1KB chunks)
            int row = chunk * 2 + (lane >> 5);          // 0..63
            int b = (lane & 31) * 16;                   // byte in 512B half-row
            int src = row * 1024 + (b ^ ((row & 7) << 4));
            gload16(gw + src, (char*)SW + chunk * 1024);
            gload16(go + src, (char*)SO + chunk * 1024);
        }
        asm volatile("s_waitcnt vmcnt(0)\n\ts_barrier" ::: "memory");
        __builtin_amdgcn_sched_barrier(0);
        const char* swp = (const char*)SW;
        const char* sop = (const char*)SO;
#pragma unroll
        for (int kk = 0; kk < 8; ++kk) {
            int ko = (kk * 64 + quad * 16) ^ cs;
            bf16x8 a = ldb8((const unsigned short*)(swp + arow + ko));
#pragma unroll
            for (int n = 0; n < 4; ++n) {
                bf16x8 bfr = ldb8((const unsigned short*)(sop + (n * 16 + col16) * 512 + ko));
                acc[n] = __builtin_amdgcn_mfma_f32_16x16x32_bf16(a, bfr, acc[n], 0, 0, 0);
            }
        }
        if (ks == 0) __syncthreads();   // all reads done before restage
    }

    // epilogue: D[o=w*16+quad*4+r][p=n*16+col16] -> LDS -> float4 stores
    float* otw = OT[w];
#pragma unroll
    for (int n = 0; n < 4; ++n)
#pragma unroll
        for (int r = 0; r < 4; ++r)
            otw[(quad * 4 + r) * 68 + n * 16 + col16] = acc[n][r];
    int r2 = lane >> 2, csg = (lane & 3) * 16;
#pragma unroll
    for (int j = 0; j < 4; ++j) {
        float4 v = *(const float4*)&otw[r2 * 68 + csg + j * 4];
        *(float4*)&out[(size_t)(o0 + w * 16 + r2) * SPAT + p0 + csg + j * 4] = v;
    }
}

// ---------------------------------------------------------------------------
// Launch
// ---------------------------------------------------------------------------
extern "C" void kernel_launch(void* const* d_in, const int* in_sizes, int n_in,
                              void* d_out, int out_size, void* d_ws, size_t ws_size,
                              hipStream_t stream) {
    const float* x      = (const float*)d_in[0];
    const float* gamma  = (const float*)d_in[1];
    const float* mem_kv = (const float*)d_in[2];
    const float* w_qkv  = (const float*)d_in[3];
    const float* w_out  = (const float*)d_in[4];
    float* out = (float*)d_out;

    // workspace (bf16 unless noted): xb | wb | wob | qb | kb | vtb | obb | spb(f32)
    unsigned short* xb  = (unsigned short*)d_ws;                 // 4096*256
    unsigned short* wb  = xb + (size_t)SPAT * C_DIM;             // 1536*256
    unsigned short* wob = wb + (size_t)3 * HID * C_DIM;          // 256*512
    unsigned short* qb  = wob + (size_t)C_DIM * HID;             // 8*4096*64
    unsigned short* kb  = qb + (size_t)HEADS_N * SPAT * DHEAD;   // 8*4160*64
    unsigned short* vtb = kb + (size_t)HEADS_N * TTOKP * DHEAD;  // 8*64*4160
    unsigned short* obb = vtb + (size_t)HEADS_N * DHEAD * TTOKP; // 4096*512
    float* spb = (float*)(obb + (size_t)SPAT * HID);             // 4096

    prep_kernel<<<dim3(832), 256, 0, stream>>>(x, gamma, mem_kv, w_qkv, w_out,
                                               xb, spb, wb, wob, kb, vtb);
    qkv_mfma<<<dim3(64, 24), 256, 0, stream>>>(wb, xb, spb, qb, kb, vtb);
    attn_mfma<<<dim3(512), 256, 0, stream>>>(qb, kb, vtb, obb);
    out_mfma<<<dim3(64, 4), 256, 0, stream>>>(wob, obb, out);
}

// Round 5
// 156.924 us; speedup vs baseline: 1.8391x; 1.0640x over previous
//
#include <hip/hip_runtime.h>
#include <hip/hip_bf16.h>
#include <math.h>

// Problem constants
#define C_DIM 256      // channels
#define SPAT 4096      // h*w = 64*64
#define HEADS_N 8
#define DHEAD 64
#define MEMTOK 4
#define TTOK 4100      // MEMTOK + SPAT
#define TTOKP 4224     // padded to 33 tiles of 128
#define HID 512        // HEADS_N * DHEAD
#define PSP 72         // epilogue LDS row pitch in bf16 elems (16B-aligned)

typedef __bf16 bf16x8 __attribute__((ext_vector_type(8)));
typedef unsigned short u16x8 __attribute__((ext_vector_type(8)));
typedef float f32x4 __attribute__((ext_vector_type(4)));

static __device__ inline unsigned short f2bf(float f) {  // RNE f32->bf16
    unsigned int u = __float_as_uint(f);
    u += 0x7fffu + ((u >> 16) & 1u);
    return (unsigned short)(u >> 16);
}

static __device__ inline bf16x8 ldb8(const void* p) {
    union { u16x8 u; bf16x8 b; } t;
    t.u = *(const u16x8*)p;
    return t.b;
}

static __device__ inline unsigned int pkbf(float a, float b) {  // packed bf16 pair
    union { __bf16 h[2]; unsigned int u; } t;
    t.h[0] = (__bf16)a; t.h[1] = (__bf16)b;
    return t.u;
}

// inverse of the per-32-token V key-permutation pi (pi: [b4b3b2]->[b2b4b3]).
// Stored col c holds actual token (c&~31)|pi(c&31); writer uses pinv.
static __device__ inline int pinv(int m) {
    return (m & 3) | (((m >> 4) & 1) << 2) | (((m >> 2) & 3) << 3);
}

// async global->LDS, 16B per lane (LDS dest = wave-uniform base + lane*16)
static __device__ inline void gload16(const void* g, void* l) {
    __builtin_amdgcn_global_load_lds(
        (const __attribute__((address_space(1))) unsigned int*)g,
        (__attribute__((address_space(3))) unsigned int*)l, 16, 0, 0);
}

#define DRAIN_BAR() do { \
    asm volatile("s_waitcnt vmcnt(0)\n\ts_barrier" ::: "memory"); \
    __builtin_amdgcn_sched_barrier(0); } while (0)

// ---------------------------------------------------------------------------
// Kernel 1: prep — all elementwise work, one launch, 1088 blocks:
//  A (0..255):    x [c][p] fp32 -> xb [p][c] bf16 (LDS 64x64 transpose)
//  B (256..319):  spb[p] = 16 * rsqrt(sum_c x^2)   (fp32, exact RMSNorm)
//  C (320..511):  wb  = bf16(w_qkv * (gamma[c]+1))
//  D (512..575):  wob = bf16(w_out)
//  E (576..1087): mem_kv placement + kb/vtb zero pads (ws re-poisoned!)
// ---------------------------------------------------------------------------
__global__ __launch_bounds__(256) void prep_kernel(
    const float* __restrict__ x, const float* __restrict__ gamma,
    const float* __restrict__ mem, const float* __restrict__ wq,
    const float* __restrict__ wo,
    unsigned short* __restrict__ xb, float* __restrict__ spb,
    unsigned short* __restrict__ wb, unsigned short* __restrict__ wob,
    unsigned short* __restrict__ kb, unsigned short* __restrict__ vtb) {
    __shared__ float XT[64][65];
    __shared__ float red[4][64];
    const int bid = blockIdx.x;
    const int t = threadIdx.x;
    if (bid < 256) {              // A: transpose-cast x
        int p0 = (bid & 63) * 64, c0 = (bid >> 6) * 64;
#pragma unroll
        for (int i = 0; i < 4; ++i) {
            int cl = i * 16 + (t >> 4), p4 = (t & 15) * 4;
            *(float4*)&XT[cl][p4] = *(const float4*)&x[(size_t)(c0 + cl) * SPAT + p0 + p4];
        }
        __syncthreads();
        int pl = t >> 2, cs = (t & 3) * 16;
        u16x8 a, b;
#pragma unroll
        for (int j = 0; j < 8; ++j) a[j] = f2bf(XT[cs + j][pl]);
#pragma unroll
        for (int j = 0; j < 8; ++j) b[j] = f2bf(XT[cs + 8 + j][pl]);
        *(u16x8*)&xb[(size_t)(p0 + pl) * C_DIM + c0 + cs] = a;
        *(u16x8*)&xb[(size_t)(p0 + pl) * C_DIM + c0 + cs + 8] = b;
    } else if (bid < 320) {       // B: norms
        int p = (bid - 256) * 64 + (t & 63);
        int g = t >> 6;
        float ss = 0.f;
        for (int c = g * 64; c < g * 64 + 64; ++c) {
            float v = x[(size_t)c * SPAT + p];
            ss += v * v;
        }
        red[g][t & 63] = ss;
        __syncthreads();
        if (g == 0) {
            int lp = t & 63;
            float tot = red[0][lp] + red[1][lp] + red[2][lp] + red[3][lp];
            spb[p] = rsqrtf(tot) * 16.0f;
        }
    } else if (bid < 512) {       // C: wb = bf16(wq * (gamma+1)), 8 elems/thread
        size_t idx = ((size_t)(bid - 320) * 256 + t) * 8;
        int c0 = (int)(idx & 255);
        float4 f0 = *(const float4*)&wq[idx];
        float4 f1 = *(const float4*)&wq[idx + 4];
        float4 g0 = *(const float4*)&gamma[c0];
        float4 g1 = *(const float4*)&gamma[c0 + 4];
        u16x8 pk;
        pk[0] = f2bf(f0.x * (g0.x + 1.f)); pk[1] = f2bf(f0.y * (g0.y + 1.f));
        pk[2] = f2bf(f0.z * (g0.z + 1.f)); pk[3] = f2bf(f0.w * (g0.w + 1.f));
        pk[4] = f2bf(f1.x * (g1.x + 1.f)); pk[5] = f2bf(f1.y * (g1.y + 1.f));
        pk[6] = f2bf(f1.z * (g1.z + 1.f)); pk[7] = f2bf(f1.w * (g1.w + 1.f));
        *(u16x8*)&wb[idx] = pk;
    } else if (bid < 576) {       // D: wob = bf16(wo)
        size_t idx = ((size_t)(bid - 512) * 256 + t) * 8;
        float4 f0 = *(const float4*)&wo[idx];
        float4 f1 = *(const float4*)&wo[idx + 4];
        u16x8 pk;
        pk[0] = f2bf(f0.x); pk[1] = f2bf(f0.y); pk[2] = f2bf(f0.z); pk[3] = f2bf(f0.w);
        pk[4] = f2bf(f1.x); pk[5] = f2bf(f1.y); pk[6] = f2bf(f1.z); pk[7] = f2bf(f1.w);
        *(u16x8*)&wob[idx] = pk;
    } else {                      // E: mem_kv + zero pads (131072 threads)
        int i = (bid - 576) * 256 + t;
        if (i < 4096) {
            int d = i & 63, m = (i >> 6) & 3, h = (i >> 8) & 7, s = (i >> 11) & 1;
            unsigned short val = f2bf(mem[i]);
            // pinv fixes 0..3, so mem V tokens land at cols 0..3 unchanged
            if (s == 0) kb[(size_t)h * TTOKP * 64 + m * 64 + d] = val;
            else        vtb[((size_t)h * 64 + d) * TTOKP + m] = val;
        } else {
            int z = i - 4096;              // 0..126975
            if (z < 63488) {               // kb pad rows 4100..4223 (124/head)
                int h = z / 7936, r = z % 7936;
                int row = TTOK + r / 64, d = r % 64;
                kb[(size_t)h * TTOKP * 64 + row * 64 + d] = 0;
            } else {                       // vtb pad cols 4100..4223
                z -= 63488;
                int h = z / 7936, r = z % 7936;
                int d = r / 124, tcol = TTOK + r % 124;
                vtb[((size_t)h * 64 + d) * TTOKP + tcol] = 0;
            }
        }
    }
}

// ---------------------------------------------------------------------------
// Kernel 2: QKV GEMM on MFMA (bf16 in, fp32 accum, bf16 out).
// C[o][p] = sp[p] * sum_c wb[o][c] * xb[p][c].  K=256 as 2 chunks of 128,
// double-buffered: stage(c+1) overlaps compute(c).  LDS chunk layout
// [64 rows][256B] with XOR swizzle (slot ^= row&7) on both sides.
// V store is key-permuted by pinv (per-32 tokens) for attn's register-P PV.
// ---------------------------------------------------------------------------
__global__ __launch_bounds__(256) void qkv_mfma(const unsigned short* __restrict__ wb,
                                                const unsigned short* __restrict__ xb,
                                                const float* __restrict__ spb,
                                                unsigned short* __restrict__ qb,
                                                unsigned short* __restrict__ kb,
                                                unsigned short* __restrict__ vtb) {
    const int tile_p = blockIdx.x;      // 0..63
    const int tile_o = blockIdx.y;      // 0..23
    const int p0 = tile_p * 64, o0 = tile_o * 64;
    __shared__ unsigned short LB[4][64 * 128];  // W0,X0,W1,X1 chunk buffers (16KB each)

    const int t = threadIdx.x;
    const int w = t >> 6, lane = t & 63;
    const int col16 = lane & 15, quad = lane >> 4;
    const int c7 = col16 & 7;
    const char* gw = (const char*)(wb + (size_t)o0 * C_DIM);
    const char* gx = (const char*)(xb + (size_t)p0 * C_DIM);

    auto STG = [&](int ck, unsigned short* SWb, unsigned short* SXb) {
#pragma unroll
        for (int i = 0; i < 4; ++i) {
            int c4 = w * 4 + i;                       // 1KB chunk
            int row = c4 * 4 + (lane >> 4);           // 0..63
            int sl = (((lane & 15) ^ (row & 7)) << 4);
            size_t src = (size_t)row * 512 + ck * 256 + sl;
            gload16(gw + src, (char*)SWb + c4 * 1024);
            gload16(gx + src, (char*)SXb + c4 * 1024);
        }
    };

    f32x4 acc[4];
#pragma unroll
    for (int n = 0; n < 4; ++n) acc[n] = (f32x4){0.f, 0.f, 0.f, 0.f};
    const int arow = (w * 16 + col16) * 256;

    auto COMP = [&](const unsigned short* SWb, const unsigned short* SXb) {
#pragma unroll
        for (int kkl = 0; kkl < 4; ++kkl) {
            int ko = (((kkl * 4 + quad) ^ c7) << 4);
            bf16x8 a = ldb8((const char*)SWb + arow + ko);
#pragma unroll
            for (int n = 0; n < 4; ++n) {
                bf16x8 b = ldb8((const char*)SXb + (n * 16 + col16) * 256 + ko);
                acc[n] = __builtin_amdgcn_mfma_f32_16x16x32_bf16(a, b, acc[n], 0, 0, 0);
            }
        }
    };

    STG(0, LB[0], LB[1]);
    DRAIN_BAR();
    STG(1, LB[2], LB[3]);     // prefetch chunk 1 under chunk-0 compute
    COMP(LB[0], LB[1]);
    DRAIN_BAR();
    COMP(LB[2], LB[3]);

    // --- epilogue: apply sp[p] (and QSC for q), store ---
    float spv[4];
#pragma unroll
    for (int n = 0; n < 4; ++n) spv[n] = spb[p0 + n * 16 + col16];

    const int sec = tile_o >> 3, h = tile_o & 7;
    if (sec < 2) {
        const float qsc = (sec == 0) ? 0.125f * 1.4426950408889634f : 1.0f;
        unsigned short* Ot = &LB[0][0];               // reuse, pitch PSP
        __syncthreads();                              // all MFMA LDS reads done
#pragma unroll
        for (int n = 0; n < 4; ++n) {
            float s = qsc * spv[n];
            ushort4 v4 = {f2bf(acc[n][0] * s), f2bf(acc[n][1] * s),
                          f2bf(acc[n][2] * s), f2bf(acc[n][3] * s)};
            *(ushort4*)&Ot[(n * 16 + col16) * PSP + w * 16 + quad * 4] = v4;
        }
        __syncthreads();
        int prow = t >> 2, dseg = t & 3;
        u16x8 va = *(u16x8*)&Ot[prow * PSP + dseg * 16];
        u16x8 vb = *(u16x8*)&Ot[prow * PSP + dseg * 16 + 8];
        unsigned short* dst = (sec == 0)
            ? qb + (size_t)h * SPAT * 64 + (size_t)(p0 + prow) * 64
            : kb + (size_t)h * TTOKP * 64 + (size_t)(MEMTOK + p0 + prow) * 64;
        *(u16x8*)&dst[dseg * 16] = va;
        *(u16x8*)&dst[dseg * 16 + 8] = vb;
    } else {   // v: scatter to vtb[h][d][pinv-permuted token col]
        unsigned short* dst = vtb + (size_t)h * 64 * TTOKP;
#pragma unroll
        for (int n = 0; n < 4; ++n) {
            int tg = MEMTOK + p0 + n * 16 + col16;
            int c = (tg & ~31) | pinv(tg & 31);
            float s = spv[n];
#pragma unroll
            for (int r = 0; r < 4; ++r)
                dst[(size_t)(w * 16 + quad * 4 + r) * TTOKP + c] = f2bf(acc[n][r] * s);
        }
    }
}

// ---------------------------------------------------------------------------
// Kernel 3: flash attention, bf16 MFMA, fp32 accum.  KVBLK=128, 33 steps.
// Swapped-operand QK^T (lane owns one q-row).  P never touches LDS: V's key
// axis is pi-permuted so the PV B-fragment is a pure register repack of the
// exp'd scores (pa_f[j] = e[2f+(j>>2)][j&3]).  K/V double-buffered via
// global_load_lds, one fused vmcnt(0)+s_barrier per step (R2-verified).
// Output obb[p][h*64+d] bf16 via per-wave LDS transpose (buffer reuse).
// ---------------------------------------------------------------------------
__global__ __launch_bounds__(256) void attn_mfma(const unsigned short* __restrict__ qb,
                                                 const unsigned short* __restrict__ kb,
                                                 const unsigned short* __restrict__ vtb,
                                                 unsigned short* __restrict__ obb) {
    const int h  = blockIdx.x & 7;           // head-pinned XCD locality
    const int p0 = (blockIdx.x >> 3) * 64;

    __shared__ unsigned short LA[4][64 * 128];   // Ks0,Vs0,Ks1,Vs1 (16KB each)

    const int t = threadIdx.x;
    const int w = t >> 6;
    const int lane = t & 63;
    const int col16 = lane & 15;
    const int quad = lane >> 4;
    const int cswz = col16 & 7;
    const int sw0 = ((quad ^ cswz) << 4);
    const int sw1 = (((quad + 4) ^ cswz) << 4);

    const unsigned short* qh = qb + (size_t)h * SPAT * 64;
    const char* khb = (const char*)(kb + (size_t)h * TTOKP * 64);
    const char* vhb = (const char*)(vtb + (size_t)h * 64 * TTOKP);

    bf16x8 aq0 = ldb8(&qh[(size_t)(p0 + w * 16 + col16) * 64 + quad * 8]);
    bf16x8 aq1 = ldb8(&qh[(size_t)(p0 + w * 16 + col16) * 64 + 32 + quad * 8]);

    float m_i = -1e30f, l_i = 0.f;
    f32x4 Oa[4];
#pragma unroll
    for (int n = 0; n < 4; ++n) Oa[n] = (f32x4){0.f, 0.f, 0.f, 0.f};

    // stage one 128-key tile: K = 128 rows x 128B, V = 64 rows x 256B
    auto STAGE = [&](int tb, unsigned short* Kd, unsigned short* Vd) {
#pragma unroll
        for (int i = 0; i < 4; ++i) {
            int ck = w * 4 + i;
            int krow = ck * 8 + (lane >> 3);                 // 0..127
            int kcol = (((lane & 7) ^ (lane >> 3)) << 4);    // krow&7 == lane>>3
            gload16(khb + (size_t)(tb * 128 + krow) * 128 + kcol, (char*)Kd + ck * 1024);
            int vrow = ck * 4 + (lane >> 4);                 // 0..63 (d)
            int vcol = (((lane & 15) ^ (vrow & 7)) << 4);
            gload16(vhb + (size_t)vrow * (TTOKP * 2) + (size_t)tb * 256 + vcol,
                    (char*)Vd + ck * 1024);
        }
    };

    auto STEP = [&](int tile, const unsigned short* Kc_, const unsigned short* Vc_,
                    unsigned short* Ksn, unsigned short* Vsn, bool stage, bool last) {
        if (stage) STAGE(tile + 1, Ksn, Vsn);

        const char* Kc = (const char*)Kc_;
        const char* Vc = (const char*)Vc_;

        // S^T: sv[n][r] = score for key n*16+quad*4+r, q = col16 (per wave)
        f32x4 sv[8];
#pragma unroll
        for (int n = 0; n < 8; ++n) {
            sv[n] = (f32x4){0.f, 0.f, 0.f, 0.f};
            bf16x8 bk0 = ldb8(Kc + (n * 16 + col16) * 128 + sw0);
            bf16x8 bk1 = ldb8(Kc + (n * 16 + col16) * 128 + sw1);
            sv[n] = __builtin_amdgcn_mfma_f32_16x16x32_bf16(bk0, aq0, sv[n], 0, 0, 0);
            sv[n] = __builtin_amdgcn_mfma_f32_16x16x32_bf16(bk1, aq1, sv[n], 0, 0, 0);
        }

        if (last) {   // final tile: only tokens 4096..4099 valid (n==0,quad==0)
#pragma unroll
            for (int n = 0; n < 8; ++n)
#pragma unroll
                for (int r = 0; r < 4; ++r)
                    if ((n | quad) != 0) sv[n][r] = -1e30f;
        }

        // row max: 31 local fmax (tree) + 2 shfl
        float mx[8];
#pragma unroll
        for (int n = 0; n < 8; ++n)
            mx[n] = fmaxf(fmaxf(sv[n][0], sv[n][1]), fmaxf(sv[n][2], sv[n][3]));
        float rm = fmaxf(fmaxf(fmaxf(mx[0], mx[1]), fmaxf(mx[2], mx[3])),
                         fmaxf(fmaxf(mx[4], mx[5]), fmaxf(mx[6], mx[7])));
        rm = fmaxf(rm, __shfl_xor(rm, 16, 64));
        rm = fmaxf(rm, __shfl_xor(rm, 32, 64));

        float mn = fmaxf(m_i, rm);
        float al = __builtin_amdgcn_exp2f(m_i - mn);
        m_i = mn;

        // exp in place + row sum
        float sm[8];
#pragma unroll
        for (int n = 0; n < 8; ++n) {
            float e0 = __builtin_amdgcn_exp2f(sv[n][0] - mn);
            float e1 = __builtin_amdgcn_exp2f(sv[n][1] - mn);
            float e2 = __builtin_amdgcn_exp2f(sv[n][2] - mn);
            float e3 = __builtin_amdgcn_exp2f(sv[n][3] - mn);
            sv[n][0] = e0; sv[n][1] = e1; sv[n][2] = e2; sv[n][3] = e3;
            sm[n] = (e0 + e1) + (e2 + e3);
        }
        float rs = ((sm[0] + sm[1]) + (sm[2] + sm[3])) +
                   ((sm[4] + sm[5]) + (sm[6] + sm[7]));
        rs += __shfl_xor(rs, 16, 64);
        rs += __shfl_xor(rs, 32, 64);
        l_i = l_i * al + rs;

#pragma unroll
        for (int n = 0; n < 4; ++n) {
            Oa[n][0] *= al; Oa[n][1] *= al; Oa[n][2] *= al; Oa[n][3] *= al;
        }

        // PV: P fragments straight from registers (pi-permuted V keys)
#pragma unroll
        for (int f = 0; f < 4; ++f) {
            union { unsigned int u[4]; bf16x8 v; } pu;
            pu.u[0] = pkbf(sv[2 * f][0], sv[2 * f][1]);
            pu.u[1] = pkbf(sv[2 * f][2], sv[2 * f][3]);
            pu.u[2] = pkbf(sv[2 * f + 1][0], sv[2 * f + 1][1]);
            pu.u[3] = pkbf(sv[2 * f + 1][2], sv[2 * f + 1][3]);
            int vo = (((f * 4 + quad) ^ cswz) << 4);
#pragma unroll
            for (int n = 0; n < 4; ++n) {
                bf16x8 bv = ldb8(Vc + (n * 16 + col16) * 256 + vo);
                Oa[n] = __builtin_amdgcn_mfma_f32_16x16x32_bf16(bv, pu.v, Oa[n], 0, 0, 0);
            }
        }

        if (!last) DRAIN_BAR();
    };

    STAGE(0, LA[0], LA[1]);
    DRAIN_BAR();
    for (int b = 0; b < 32; b += 2) {
        STEP(b,     LA[0], LA[1], LA[2], LA[3], true, false);
        STEP(b + 1, LA[2], LA[3], LA[0], LA[1], true, false);
    }
    STEP(32, LA[0], LA[1], LA[2], LA[3], false, true);

    // epilogue: O^T/l -> bf16, per-wave LDS transpose -> obb[p][h*64+d]
    __syncthreads();                                  // all waves done reading LA
    float inv = 1.0f / l_i;
    __bf16* ot = (__bf16*)&LA[0][0] + (size_t)w * 16 * PSP;
#pragma unroll
    for (int n = 0; n < 4; ++n) {
        *(unsigned int*)&ot[col16 * PSP + n * 16 + quad * 4] =
            pkbf(Oa[n][0] * inv, Oa[n][1] * inv);
        *(unsigned int*)&ot[col16 * PSP + n * 16 + quad * 4 + 2] =
            pkbf(Oa[n][2] * inv, Oa[n][3] * inv);
    }
    int q2 = lane >> 2, dseg = (lane & 3) * 16;
    const unsigned short* otr = (const unsigned short*)ot;
    u16x8 o0v = *(const u16x8*)&otr[q2 * PSP + dseg];
    u16x8 o1v = *(const u16x8*)&otr[q2 * PSP + dseg + 8];
    unsigned short* dst = obb + (size_t)(p0 + w * 16 + q2) * HID + h * DHEAD + dseg;
    *(u16x8*)&dst[0] = o0v;
    *(u16x8*)&dst[8] = o1v;
}

// ---------------------------------------------------------------------------
// Kernel 4: out projection on MFMA (bf16 in, fp32 accum, fp32 out).
// out[o][p] = sum_hd wob[o][hd] * obb[p][hd].  K=512 as 4 chunks of 128,
// double-buffered staging (stage c+1 under compute c).
// ---------------------------------------------------------------------------
__global__ __launch_bounds__(256) void out_mfma(const unsigned short* __restrict__ wob,
                                                const unsigned short* __restrict__ obb,
                                                float* __restrict__ out) {
    const int p0 = blockIdx.x * 64;
    const int o0 = blockIdx.y * 64;
    __shared__ unsigned short LB[4][64 * 128];   // W0,O0,W1,O1 chunk buffers

    const int t = threadIdx.x;
    const int w = t >> 6, lane = t & 63;
    const int col16 = lane & 15, quad = lane >> 4;
    const int c7 = col16 & 7;
    const char* gw = (const char*)(wob + (size_t)o0 * HID);
    const char* go = (const char*)(obb + (size_t)p0 * HID);

    auto STG = [&](int ck, unsigned short* SWb, unsigned short* SOb) {
#pragma unroll
        for (int i = 0; i < 4; ++i) {
            int c4 = w * 4 + i;
            int row = c4 * 4 + (lane >> 4);
            int sl = (((lane & 15) ^ (row & 7)) << 4);
            size_t src = (size_t)row * 1024 + ck * 256 + sl;
            gload16(gw + src, (char*)SWb + c4 * 1024);
            gload16(go + src, (char*)SOb + c4 * 1024);
        }
    };

    f32x4 acc[4];
#pragma unroll
    for (int n = 0; n < 4; ++n) acc[n] = (f32x4){0.f, 0.f, 0.f, 0.f};
    const int arow = (w * 16 + col16) * 256;

    auto COMP = [&](const unsigned short* SWb, const unsigned short* SOb) {
#pragma unroll
        for (int kkl = 0; kkl < 4; ++kkl) {
            int ko = (((kkl * 4 + quad) ^ c7) << 4);
            bf16x8 a = ldb8((const char*)SWb + arow + ko);
#pragma unroll
            for (int n = 0; n < 4; ++n) {
                bf16x8 b = ldb8((const char*)SOb + (n * 16 + col16) * 256 + ko);
                acc[n] = __builtin_amdgcn_mfma_f32_16x16x32_bf16(a, b, acc[n], 0, 0, 0);
            }
        }
    };

    STG(0, LB[0], LB[1]);
    DRAIN_BAR();
    STG(1, LB[2], LB[3]);  COMP(LB[0], LB[1]);  DRAIN_BAR();
    STG(2, LB[0], LB[1]);  COMP(LB[2], LB[3]);  DRAIN_BAR();
    STG(3, LB[2], LB[3]);  COMP(LB[0], LB[1]);  DRAIN_BAR();
    COMP(LB[2], LB[3]);

    // epilogue: D[o][p] -> per-wave LDS transpose -> coalesced float4 stores
    __syncthreads();
    float* otw = (float*)&LB[0][0] + (size_t)w * (16 * 68);
#pragma unroll
    for (int n = 0; n < 4; ++n)
#pragma unroll
        for (int r = 0; r < 4; ++r)
            otw[(quad * 4 + r) * 68 + n * 16 + col16] = acc[n][r];
    int r2 = lane >> 2, csg = (lane & 3) * 16;
#pragma unroll
    for (int j = 0; j < 4; ++j) {
        float4 v = *(const float4*)&otw[r2 * 68 + csg + j * 4];
        *(float4*)&out[(size_t)(o0 + w * 16 + r2) * SPAT + p0 + csg + j * 4] = v;
    }
}

// ---------------------------------------------------------------------------
// Launch
// ---------------------------------------------------------------------------
extern "C" void kernel_launch(void* const* d_in, const int* in_sizes, int n_in,
                              void* d_out, int out_size, void* d_ws, size_t ws_size,
                              hipStream_t stream) {
    const float* x      = (const float*)d_in[0];
    const float* gamma  = (const float*)d_in[1];
    const float* mem_kv = (const float*)d_in[2];
    const float* w_qkv  = (const float*)d_in[3];
    const float* w_out  = (const float*)d_in[4];
    float* out = (float*)d_out;

    // workspace (bf16 unless noted): xb | wb | wob | qb | kb | vtb | obb | spb(f32)
    unsigned short* xb  = (unsigned short*)d_ws;                 // 4096*256
    unsigned short* wb  = xb + (size_t)SPAT * C_DIM;             // 1536*256
    unsigned short* wob = wb + (size_t)3 * HID * C_DIM;          // 256*512
    unsigned short* qb  = wob + (size_t)C_DIM * HID;             // 8*4096*64
    unsigned short* kb  = qb + (size_t)HEADS_N * SPAT * DHEAD;   // 8*4224*64
    unsigned short* vtb = kb + (size_t)HEADS_N * TTOKP * DHEAD;  // 8*64*4224
    unsigned short* obb = vtb + (size_t)HEADS_N * DHEAD * TTOKP; // 4096*512
    float* spb = (float*)(obb + (size_t)SPAT * HID);             // 4096

    prep_kernel<<<dim3(1088), 256, 0, stream>>>(x, gamma, mem_kv, w_qkv, w_out,
                                                xb, spb, wb, wob, kb, vtb);
    qkv_mfma<<<dim3(64, 24), 256, 0, stream>>>(wb, xb, spb, qb, kb, vtb);
    attn_mfma<<<dim3(512), 256, 0, stream>>>(qb, kb, vtb, obb);
    out_mfma<<<dim3(64, 4), 256, 0, stream>>>(wob, obb, out);
}